// Round 24
// baseline (149.881 us; speedup 1.0000x reference)
//
#include <hip/hip_runtime.h>
#include <hip/hip_bf16.h>
#include <math.h>

#define SLEN 4096
#define NF   512
#define LOG2E 1.44269504f

typedef short s8v  __attribute__((ext_vector_type(8)));
typedef short s4v  __attribute__((ext_vector_type(4)));
typedef float f4v  __attribute__((ext_vector_type(4)));
typedef float f16v __attribute__((ext_vector_type(16)));
typedef __attribute__((address_space(1))) const unsigned int gu32;
typedef __attribute__((address_space(3))) unsigned int lu32;

static __device__ __forceinline__ short f2bf(float f) {
  union { float f; unsigned int u; } v; v.f = f;
  unsigned int u = v.u;
  unsigned int r = (u + 0x7FFFu + ((u >> 16) & 1u)) >> 16;
  return (short)r;
}

// ---------------------------------------------------------------------------
// prep_all (merged): blocks [0,2048): x fp32->bf16; block 2048: bqs;
// blocks (2048,2057): maskl; blocks [2057,2313): W -> WT bf16 transpose
// (wq prescaled by 0.125*log2e).
// ---------------------------------------------------------------------------
__global__ __launch_bounds__(256) void prep_all(
    const float* __restrict__ x, const float* __restrict__ bq,
    const float* __restrict__ mask,
    const float* __restrict__ wq, const float* __restrict__ wk,
    const float* __restrict__ wv, const float* __restrict__ wo,
    short* __restrict__ xb, float* __restrict__ bqs,
    float* __restrict__ maskl, short* __restrict__ wt) {
  __shared__ short T[64][68];
  const int b = blockIdx.x, tid = threadIdx.x;
  if (b < 2048) {
    size_t i = ((size_t)b * 256 + tid) * 8;
    float4 a = *(const float4*)(x + i);
    float4 c = *(const float4*)(x + i + 4);
    s8v o;
    o[0] = f2bf(a.x); o[1] = f2bf(a.y); o[2] = f2bf(a.z); o[3] = f2bf(a.w);
    o[4] = f2bf(c.x); o[5] = f2bf(c.y); o[6] = f2bf(c.z); o[7] = f2bf(c.w);
    *(s8v*)(xb + i) = o;
  } else if (b == 2048) {
#pragma unroll
    for (int j = 0; j < 2; j++) {
      int i = tid + 256 * j;
      bqs[i] = bq[i] * (0.125f * LOG2E);
    }
  } else if (b < 2057) {
    int i4 = ((b - 2049) * 1024) + tid * 4;
    float4 m = *(const float4*)(mask + i4);
    m.x *= LOG2E; m.y *= LOG2E; m.z *= LOG2E; m.w *= LOG2E;
    *(float4*)(maskl + i4) = m;
  } else {
    const int bp = b - 2057;
    const int bz = bp >> 6, t = bp & 63;
    const float* W = (bz == 0) ? wq : (bz == 1) ? wk : (bz == 2) ? wv : wo;
    const float scale = (bz == 0) ? 0.125f * LOG2E : 1.0f;
    const int tk = t & 7, tn = t >> 3;
#pragma unroll
    for (int p = 0; p < 4; p++) {
      int c = tid + 256 * p;
      int kk = c >> 4, c4 = c & 15;
      float4 v = *(const float4*)(W + (size_t)(tk * 64 + kk) * NF + tn * 64 + c4 * 4);
      T[kk][c4 * 4 + 0] = f2bf(v.x * scale);
      T[kk][c4 * 4 + 1] = f2bf(v.y * scale);
      T[kk][c4 * 4 + 2] = f2bf(v.z * scale);
      T[kk][c4 * 4 + 3] = f2bf(v.w * scale);
    }
    __syncthreads();
#pragma unroll
    for (int p = 0; p < 2; p++) {
      int c = tid + 256 * p;
      int nrow = c >> 3, ks = c & 7;
      s8v g;
#pragma unroll
      for (int j = 0; j < 8; j++) g[j] = T[ks * 8 + j][nrow];
      *(s8v*)(wt + (size_t)bz * NF * NF + (size_t)(tn * 64 + nrow) * NF + tk * 64 + ks * 8) = g;
    }
  }
}

// ---------------------------------------------------------------------------
// qkv_proj (bf16 inputs): C[8192,512] = xb @ WT[z]^T + bias.  gl_lds staging.
// ---------------------------------------------------------------------------
__global__ __launch_bounds__(256) void qkv_proj(
    const short* __restrict__ xb, const short* __restrict__ wt,
    const float* __restrict__ bqs, const float* __restrict__ bk,
    const float* __restrict__ bv,
    short* __restrict__ qo, short* __restrict__ ko, short* __restrict__ vo)
{
  const int z = blockIdx.z;
  const short* WT   = wt + (size_t)z * NF * NF;
  const float* bias = (z == 0) ? bqs : (z == 1) ? bk : bv;
  const int m0 = blockIdx.x * 128;
  const int n0 = blockIdx.y * 128;

  __shared__ short Al[2][128][32];
  __shared__ short Bl[2][128][32];

  const int tid = threadIdx.x;
  const int wave = tid >> 6, lane = tid & 63;
  const int lg = lane >> 4, lr = lane & 15;
  const int wm = wave >> 1, wn = wave & 1;
  const int grow = lane >> 2;
  const int gsl  = lane & 3;

  f4v acc[4][4];
#pragma unroll
  for (int i = 0; i < 4; i++)
#pragma unroll
    for (int j = 0; j < 4; j++) acc[i][j] = (f4v){0.f, 0.f, 0.f, 0.f};

#pragma unroll
  for (int c = 0; c < 2; c++) {
    int row = wave * 32 + c * 16 + grow;
    __builtin_amdgcn_global_load_lds(
        (gu32*)(xb + (size_t)(m0 + row) * NF + gsl * 8),
        (lu32*)&Al[0][wave * 32 + c * 16][0], 16, 0, 0);
    __builtin_amdgcn_global_load_lds(
        (gu32*)(WT + (size_t)(n0 + row) * NF + gsl * 8),
        (lu32*)&Bl[0][wave * 32 + c * 16][0], 16, 0, 0);
  }

#pragma unroll
  for (int ki = 0; ki < 16; ki++) {
    const int cur = ki & 1;
    __syncthreads();

    if (ki + 1 < 16) {
      const int kn = (ki + 1) * 32;
#pragma unroll
      for (int c = 0; c < 2; c++) {
        int row = wave * 32 + c * 16 + grow;
        __builtin_amdgcn_global_load_lds(
            (gu32*)(xb + (size_t)(m0 + row) * NF + kn + gsl * 8),
            (lu32*)&Al[cur ^ 1][wave * 32 + c * 16][0], 16, 0, 0);
        __builtin_amdgcn_global_load_lds(
            (gu32*)(WT + (size_t)(n0 + row) * NF + kn + gsl * 8),
            (lu32*)&Bl[cur ^ 1][wave * 32 + c * 16][0], 16, 0, 0);
      }
    }

    s8v af[4], bf[4];
#pragma unroll
    for (int f = 0; f < 4; f++) af[f] = *(const s8v*)&Al[cur][wm * 64 + f * 16 + lr][lg * 8];
#pragma unroll
    for (int f = 0; f < 4; f++) bf[f] = *(const s8v*)&Bl[cur][wn * 64 + f * 16 + lr][lg * 8];
#pragma unroll
    for (int i = 0; i < 4; i++)
#pragma unroll
      for (int j = 0; j < 4; j++)
        acc[i][j] = __builtin_amdgcn_mfma_f32_16x16x32_bf16(af[i], bf[j], acc[i][j], 0, 0, 0);
  }

#pragma unroll
  for (int i = 0; i < 4; i++) {
    int mbase = m0 + wm * 64 + i * 16 + lg * 4;
#pragma unroll
    for (int j = 0; j < 4; j++) {
      int n = n0 + wn * 64 + j * 16 + lr;
      float bval = bias[n];
      int h = n >> 6, d = n & 63;
      if (z == 2) {
        int b = mbase >> 12, s = mbase & 4095;
        s4v pk;
#pragma unroll
        for (int r = 0; r < 4; r++) pk[r] = f2bf(acc[i][j][r] + bval);
        *(s4v*)(vo + ((size_t)((b * 8 + h) * 64 + d)) * SLEN + s) = pk;
      } else {
        short* dst = (z == 0) ? qo : ko;
#pragma unroll
        for (int r = 0; r < 4; r++) {
          int m = mbase + r;
          int b = m >> 12, s = m & 4095;
          dst[((size_t)((b * 8 + h)) * SLEN + s) * 64 + d] = f2bf(acc[i][j][r] + bval);
        }
      }
    }
  }
}

// ---------------------------------------------------------------------------
// attn: r18 body with ONE reorder: exp/PV interleaved per tt AFTER both QK
// chains: QK(0),QK(1) -> exp(0) -> PV(ks0,1) -> exp(1) -> PV(ks2,3).
// Keeps both QK MFMA chains parallel (r15's serialization avoided) while
// PV(0)'s matrix-pipe work overlaps exp(1)'s trans-pipe work.
// lacc/oa accumulation order unchanged (ks 0,1,2,3) -> bitwise identical.
// ---------------------------------------------------------------------------
template<int SPLIT>
__global__ __launch_bounds__(256) void attn(
    const short* __restrict__ q, const short* __restrict__ k,
    const short* __restrict__ vt, const float* __restrict__ maskl,
    short* __restrict__ ctx, float* __restrict__ poa, float* __restrict__ plc)
{
  const int KVLEN = SLEN / SPLIT;
  const int NT = KVLEN / 64;
  __shared__ short Kl[2][64][64];   // [buf][t][d], 16B slots XOR-swizzled by t&7
  __shared__ short Vl[2][64][64];   // [buf][d][t], swizzled by d&7

  const int tid = threadIdx.x;
  const int wave = tid >> 6, lane = tid & 63;
  const int h = lane >> 5, ln = lane & 31;

  const int x = blockIdx.x;
  const int c8 = x & 7, idx = x >> 3;
  const int bhsp = c8 + 8 * (idx >> 5);
  const int qb = idx & 31;
  const int bh = bhsp & 15;
  const int sp = bhsp >> 4;               // 0 for SPLIT=1
  const int bb = bh >> 3, hh = bh & 7;
  const int q0 = qb * 128 + wave * 32;

  const short* qp = q + ((size_t)bh * SLEN + q0 + ln) * 64 + h * 8;
  s8v qf[4];
#pragma unroll
  for (int d = 0; d < 4; d++) qf[d] = *(const s8v*)(qp + d * 16);

  s8v ones;
#pragma unroll
  for (int j = 0; j < 8; j++) ones[j] = (short)0x3F80;   // bf16 1.0

  f16v oa[2], lacc;
#pragma unroll
  for (int i = 0; i < 16; i++) { oa[0][i] = 0.f; oa[1][i] = 0.f; lacc[i] = 0.f; }

  const short* kg = k + (size_t)bh * SLEN * 64 + (size_t)sp * KVLEN * 64;
  const short* vg = vt + (size_t)bh * 64 * SLEN + (size_t)sp * KVLEN;
  const float* mp = maskl + (size_t)bb * SLEN + (size_t)sp * KVLEN;

  const int srow = tid >> 3, ss = tid & 7;
  const int sws = (ss ^ (srow & 7)) * 8;

  s8v kr0 = *(const s8v*)(kg + (size_t)srow * 64 + ss * 8);
  s8v kr1 = *(const s8v*)(kg + (size_t)(srow + 32) * 64 + ss * 8);
  s8v vr0 = *(const s8v*)(vg + (size_t)srow * SLEN + ss * 8);
  s8v vr1 = *(const s8v*)(vg + (size_t)(srow + 32) * SLEN + ss * 8);
  *(s8v*)&Kl[0][srow][sws] = kr0;  *(s8v*)&Kl[0][srow + 32][sws] = kr1;
  *(s8v*)&Vl[0][srow][sws] = vr0;  *(s8v*)&Vl[0][srow + 32][sws] = vr1;

  for (int it = 0; it < NT; ++it) {
    const int cur = it & 1;
    const int t0 = it * 64;
    __syncthreads();

    if (it + 1 < NT) {
      kr0 = *(const s8v*)(kg + (size_t)(t0 + 64 + srow) * 64 + ss * 8);
      kr1 = *(const s8v*)(kg + (size_t)(t0 + 96 + srow) * 64 + ss * 8);
      vr0 = *(const s8v*)(vg + (size_t)srow * SLEN + t0 + 64 + ss * 8);
      vr1 = *(const s8v*)(vg + (size_t)(srow + 32) * SLEN + t0 + 64 + ss * 8);
    }

    // ---- QK^T both tt (parallel chains), mask as C-init
    f16v sa[2];
#pragma unroll
    for (int tt = 0; tt < 2; tt++) {
#pragma unroll
      for (int q4 = 0; q4 < 4; q4++) {
        float4 mv = *(const float4*)(mp + t0 + tt * 32 + q4 * 8 + h * 4);
        sa[tt][q4 * 4 + 0] = mv.x;
        sa[tt][q4 * 4 + 1] = mv.y;
        sa[tt][q4 * 4 + 2] = mv.z;
        sa[tt][q4 * 4 + 3] = mv.w;
      }
    }
    __builtin_amdgcn_s_setprio(1);
#pragma unroll
    for (int tt = 0; tt < 2; tt++) {
#pragma unroll
      for (int ds_ = 0; ds_ < 4; ds_++) {
        s8v kf = *(const s8v*)&Kl[cur][tt * 32 + ln][(((ds_ * 2 + h) ^ (ln & 7))) * 8];
        sa[tt] = __builtin_amdgcn_mfma_f32_32x32x16_bf16(kf, qf[ds_], sa[tt], 0, 0, 0);
      }
    }
    __builtin_amdgcn_s_setprio(0);

    // ---- per tt: exp/pack then its PV pair (PV(0) overlaps exp(1))
#pragma unroll
    for (int tt = 0; tt < 2; tt++) {
      unsigned int pk[4][2];
#pragma unroll
      for (int q4 = 0; q4 < 4; q4++) {
        float p0, p1, p2, p3;
        asm("v_exp_f32 %0, %1" : "=v"(p0) : "v"(sa[tt][q4 * 4 + 0]));
        asm("v_exp_f32 %0, %1" : "=v"(p1) : "v"(sa[tt][q4 * 4 + 1]));
        asm("v_exp_f32 %0, %1" : "=v"(p2) : "v"(sa[tt][q4 * 4 + 2]));
        asm("v_exp_f32 %0, %1" : "=v"(p3) : "v"(sa[tt][q4 * 4 + 3]));
        unsigned int u0, u1;
        asm("v_cvt_pk_bf16_f32 %0, %1, %2" : "=v"(u0) : "v"(p0), "v"(p1));
        asm("v_cvt_pk_bf16_f32 %0, %1, %2" : "=v"(u1) : "v"(p2), "v"(p3));
        pk[q4][0] = u0;
        pk[q4][1] = u1;
      }

      __builtin_amdgcn_s_setprio(1);
#pragma unroll
      for (int k1 = 0; k1 < 2; k1++) {
        const int ks = tt * 2 + k1;
        unsigned int s0 = h ? pk[2 * k1][0] : pk[2 * k1 + 1][0];
        unsigned int s1 = h ? pk[2 * k1][1] : pk[2 * k1 + 1][1];
        unsigned int r0 = (unsigned int)__shfl_xor((int)s0, 32);
        unsigned int r1 = (unsigned int)__shfl_xor((int)s1, 32);
        union { unsigned int u[4]; s8v v; } af;
        af.u[0] = h ? r0 : pk[2 * k1][0];
        af.u[1] = h ? r1 : pk[2 * k1][1];
        af.u[2] = h ? pk[2 * k1 + 1][0] : r0;
        af.u[3] = h ? pk[2 * k1 + 1][1] : r1;
        lacc = __builtin_amdgcn_mfma_f32_32x32x16_bf16(af.v, ones, lacc, 0, 0, 0);
#pragma unroll
        for (int dt = 0; dt < 2; dt++) {
          s8v vf = *(const s8v*)&Vl[cur][dt * 32 + ln][(((ks * 2 + h) ^ (ln & 7))) * 8];
          oa[dt] = __builtin_amdgcn_mfma_f32_32x32x16_bf16(af.v, vf, oa[dt], 0, 0, 0);
        }
      }
      __builtin_amdgcn_s_setprio(0);
    }

    if (it + 1 < NT) {
      *(s8v*)&Kl[cur ^ 1][srow][sws] = kr0;  *(s8v*)&Kl[cur ^ 1][srow + 32][sws] = kr1;
      *(s8v*)&Vl[cur ^ 1][srow][sws] = vr0;  *(s8v*)&Vl[cur ^ 1][srow + 32][sws] = vr1;
    }
  }

  if constexpr (SPLIT == 1) {
#pragma unroll
    for (int q4 = 0; q4 < 4; q4++)
#pragma unroll
      for (int i = 0; i < 4; i++) {
        float inv = 1.0f / lacc[q4 * 4 + i];
        int qrow = q0 + i + q4 * 8 + 4 * h;
        size_t base = ((size_t)bb * SLEN + qrow) * NF + hh * 64;
        ctx[base + ln]      = f2bf(oa[0][q4 * 4 + i] * inv);
        ctx[base + 32 + ln] = f2bf(oa[1][q4 * 4 + i] * inv);
      }
  } else {
#pragma unroll
    for (int dt = 0; dt < 2; dt++) {
      size_t dbase = ((size_t)(sp * 16 + bh) * 64 + dt * 32 + ln) * SLEN;
#pragma unroll
      for (int q4 = 0; q4 < 4; q4++) {
        float4 v = {oa[dt][q4 * 4 + 0], oa[dt][q4 * 4 + 1],
                    oa[dt][q4 * 4 + 2], oa[dt][q4 * 4 + 3]};
        *(float4*)(poa + dbase + q0 + q4 * 8 + 4 * h) = v;
      }
    }
    if (ln == 0) {
      size_t lbase = (size_t)(sp * 16 + bh) * SLEN;
#pragma unroll
      for (int q4 = 0; q4 < 4; q4++) {
        float4 v = {lacc[q4 * 4 + 0], lacc[q4 * 4 + 1],
                    lacc[q4 * 4 + 2], lacc[q4 * 4 + 3]};
        *(float4*)(plc + lbase + q0 + q4 * 8 + 4 * h) = v;
      }
    }
  }
}

// ---------------------------------------------------------------------------
// out_proj: out[M,512] = ctx(bf16) @ WT[3] + bo  (fp32 out), gl_lds staging.
// ---------------------------------------------------------------------------
__global__ __launch_bounds__(256) void out_proj(
    const short* __restrict__ ctx, const short* __restrict__ wt,
    const float* __restrict__ bo, float* __restrict__ out)
{
  const short* WT = wt + (size_t)3 * NF * NF;
  const int m0 = blockIdx.x * 128;
  const int n0 = blockIdx.y * 128;
  __shared__ short Al[2][128][32];
  __shared__ short Bl[2][128][32];
  const int tid = threadIdx.x;
  const int wave = tid >> 6, lane = tid & 63;
  const int lg = lane >> 4, lr = lane & 15;
  const int wm = wave >> 1, wn = wave & 1;
  const int grow = lane >> 2;
  const int gsl  = lane & 3;

  f4v acc[4][4];
#pragma unroll
  for (int i = 0; i < 4; i++)
#pragma unroll
    for (int j = 0; j < 4; j++) acc[i][j] = (f4v){0.f, 0.f, 0.f, 0.f};

#pragma unroll
  for (int c = 0; c < 2; c++) {
    int row = wave * 32 + c * 16 + grow;
    __builtin_amdgcn_global_load_lds(
        (gu32*)(ctx + (size_t)(m0 + row) * NF + gsl * 8),
        (lu32*)&Al[0][wave * 32 + c * 16][0], 16, 0, 0);
    __builtin_amdgcn_global_load_lds(
        (gu32*)(WT + (size_t)(n0 + row) * NF + gsl * 8),
        (lu32*)&Bl[0][wave * 32 + c * 16][0], 16, 0, 0);
  }

#pragma unroll
  for (int ki = 0; ki < 16; ki++) {
    const int cur = ki & 1;
    __syncthreads();

    if (ki + 1 < 16) {
      const int kn = (ki + 1) * 32;
#pragma unroll
      for (int c = 0; c < 2; c++) {
        int row = wave * 32 + c * 16 + grow;
        __builtin_amdgcn_global_load_lds(
            (gu32*)(ctx + (size_t)(m0 + row) * NF + kn + gsl * 8),
            (lu32*)&Al[cur ^ 1][wave * 32 + c * 16][0], 16, 0, 0);
        __builtin_amdgcn_global_load_lds(
            (gu32*)(WT + (size_t)(n0 + row) * NF + kn + gsl * 8),
            (lu32*)&Bl[cur ^ 1][wave * 32 + c * 16][0], 16, 0, 0);
      }
    }

    s8v af[4], bf[4];
#pragma unroll
    for (int f = 0; f < 4; f++) af[f] = *(const s8v*)&Al[cur][wm * 64 + f * 16 + lr][lg * 8];
#pragma unroll
    for (int f = 0; f < 4; f++) bf[f] = *(const s8v*)&Bl[cur][wn * 64 + f * 16 + lr][lg * 8];
#pragma unroll
    for (int i = 0; i < 4; i++)
#pragma unroll
      for (int j = 0; j < 4; j++)
        acc[i][j] = __builtin_amdgcn_mfma_f32_16x16x32_bf16(af[i], bf[j], acc[i][j], 0, 0, 0);
  }

#pragma unroll
  for (int i = 0; i < 4; i++) {
    int mbase = m0 + wm * 64 + i * 16 + lg * 4;
#pragma unroll
    for (int j = 0; j < 4; j++) {
      int n = n0 + wn * 64 + j * 16 + lr;
      float bval = bo[n];
#pragma unroll
      for (int r = 0; r < 4; r++)
        out[(size_t)(mbase + r) * NF + n] = acc[i][j][r] + bval;
    }
  }
}

// ---------------------------------------------------------------------------
extern "C" void kernel_launch(void* const* d_in, const int* in_sizes, int n_in,
                              void* d_out, int out_size, void* d_ws, size_t ws_size,
                              hipStream_t stream) {
  const float* x    = (const float*)d_in[0];
  const float* mask = (const float*)d_in[1];
  const float* wq   = (const float*)d_in[2];
  const float* bq   = (const float*)d_in[3];
  const float* wk   = (const float*)d_in[4];
  const float* bk   = (const float*)d_in[5];
  const float* wv   = (const float*)d_in[6];
  const float* bv   = (const float*)d_in[7];
  const float* wo   = (const float*)d_in[8];
  const float* bo   = (const float*)d_in[9];
  float* out = (float*)d_out;

  char* ws = (char*)d_ws;
  const size_t MB = 1024ull * 1024ull;
  short* xb    = (short*)(ws);                 // 8 MB
  short* q_ws  = (short*)(ws + 8 * MB);        // 8 MB
  short* k_ws  = (short*)(ws + 16 * MB);       // 8 MB
  short* v_ws  = (short*)(ws + 24 * MB);       // 8 MB
  short* c_ws  = (short*)(ws + 32 * MB);       // 8 MB
  short* wt    = (short*)(ws + 40 * MB);       // 2 MB
  float* bqs   = (float*)(ws + 42 * MB);       // 2 KB
  float* maskl = (float*)(ws + 43 * MB);       // 32 KB
  float* poa   = (float*)(ws + 44 * MB);       // (SPLIT=2 fallback only)
  float* plc   = (float*)(ws + 76 * MB);

  prep_all<<<2313, 256, 0, stream>>>(x, bq, mask, wq, wk, wv, wo, xb, bqs, maskl, wt);
  qkv_proj<<<dim3(64, 4, 3), 256, 0, stream>>>(xb, wt, bqs, bk, bv, q_ws, k_ws, v_ws);
  attn<1><<<512, 256, 0, stream>>>(q_ws, k_ws, v_ws, maskl, c_ws, poa, plc);
  out_proj<<<dim3(64, 4), 256, 0, stream>>>(c_ws, wt, bo, out);
}

// Round 25
// 145.843 us; speedup vs baseline: 1.0277x; 1.0277x over previous
//
#include <hip/hip_runtime.h>
#include <hip/hip_bf16.h>
#include <math.h>

#define SLEN 4096
#define NF   512
#define LOG2E 1.44269504f

typedef short s8v  __attribute__((ext_vector_type(8)));
typedef short s4v  __attribute__((ext_vector_type(4)));
typedef float f4v  __attribute__((ext_vector_type(4)));
typedef float f16v __attribute__((ext_vector_type(16)));
typedef __attribute__((address_space(1))) const unsigned int gu32;
typedef __attribute__((address_space(3))) unsigned int lu32;

static __device__ __forceinline__ short f2bf(float f) {
  union { float f; unsigned int u; } v; v.f = f;
  unsigned int u = v.u;
  unsigned int r = (u + 0x7FFFu + ((u >> 16) & 1u)) >> 16;
  return (short)r;
}

// ---------------------------------------------------------------------------
// prep_all (merged): blocks [0,2048): x fp32->bf16; block 2048: bqs;
// blocks (2048,2057): maskl; blocks [2057,2313): W -> WT bf16 transpose
// (wq prescaled by 0.125*log2e).
// ---------------------------------------------------------------------------
__global__ __launch_bounds__(256) void prep_all(
    const float* __restrict__ x, const float* __restrict__ bq,
    const float* __restrict__ mask,
    const float* __restrict__ wq, const float* __restrict__ wk,
    const float* __restrict__ wv, const float* __restrict__ wo,
    short* __restrict__ xb, float* __restrict__ bqs,
    float* __restrict__ maskl, short* __restrict__ wt) {
  __shared__ short T[64][68];
  const int b = blockIdx.x, tid = threadIdx.x;
  if (b < 2048) {
    size_t i = ((size_t)b * 256 + tid) * 8;
    float4 a = *(const float4*)(x + i);
    float4 c = *(const float4*)(x + i + 4);
    s8v o;
    o[0] = f2bf(a.x); o[1] = f2bf(a.y); o[2] = f2bf(a.z); o[3] = f2bf(a.w);
    o[4] = f2bf(c.x); o[5] = f2bf(c.y); o[6] = f2bf(c.z); o[7] = f2bf(c.w);
    *(s8v*)(xb + i) = o;
  } else if (b == 2048) {
#pragma unroll
    for (int j = 0; j < 2; j++) {
      int i = tid + 256 * j;
      bqs[i] = bq[i] * (0.125f * LOG2E);
    }
  } else if (b < 2057) {
    int i4 = ((b - 2049) * 1024) + tid * 4;
    float4 m = *(const float4*)(mask + i4);
    m.x *= LOG2E; m.y *= LOG2E; m.z *= LOG2E; m.w *= LOG2E;
    *(float4*)(maskl + i4) = m;
  } else {
    const int bp = b - 2057;
    const int bz = bp >> 6, t = bp & 63;
    const float* W = (bz == 0) ? wq : (bz == 1) ? wk : (bz == 2) ? wv : wo;
    const float scale = (bz == 0) ? 0.125f * LOG2E : 1.0f;
    const int tk = t & 7, tn = t >> 3;
#pragma unroll
    for (int p = 0; p < 4; p++) {
      int c = tid + 256 * p;
      int kk = c >> 4, c4 = c & 15;
      float4 v = *(const float4*)(W + (size_t)(tk * 64 + kk) * NF + tn * 64 + c4 * 4);
      T[kk][c4 * 4 + 0] = f2bf(v.x * scale);
      T[kk][c4 * 4 + 1] = f2bf(v.y * scale);
      T[kk][c4 * 4 + 2] = f2bf(v.z * scale);
      T[kk][c4 * 4 + 3] = f2bf(v.w * scale);
    }
    __syncthreads();
#pragma unroll
    for (int p = 0; p < 2; p++) {
      int c = tid + 256 * p;
      int nrow = c >> 3, ks = c & 7;
      s8v g;
#pragma unroll
      for (int j = 0; j < 8; j++) g[j] = T[ks * 8 + j][nrow];
      *(s8v*)(wt + (size_t)bz * NF * NF + (size_t)(tn * 64 + nrow) * NF + tk * 64 + ks * 8) = g;
    }
  }
}

// ---------------------------------------------------------------------------
// qkv_proj (bf16 inputs): C[8192,512] = xb @ WT[z]^T + bias.  gl_lds staging.
// ---------------------------------------------------------------------------
__global__ __launch_bounds__(256) void qkv_proj(
    const short* __restrict__ xb, const short* __restrict__ wt,
    const float* __restrict__ bqs, const float* __restrict__ bk,
    const float* __restrict__ bv,
    short* __restrict__ qo, short* __restrict__ ko, short* __restrict__ vo)
{
  const int z = blockIdx.z;
  const short* WT   = wt + (size_t)z * NF * NF;
  const float* bias = (z == 0) ? bqs : (z == 1) ? bk : bv;
  const int m0 = blockIdx.x * 128;
  const int n0 = blockIdx.y * 128;

  __shared__ short Al[2][128][32];
  __shared__ short Bl[2][128][32];

  const int tid = threadIdx.x;
  const int wave = tid >> 6, lane = tid & 63;
  const int lg = lane >> 4, lr = lane & 15;
  const int wm = wave >> 1, wn = wave & 1;
  const int grow = lane >> 2;
  const int gsl  = lane & 3;

  f4v acc[4][4];
#pragma unroll
  for (int i = 0; i < 4; i++)
#pragma unroll
    for (int j = 0; j < 4; j++) acc[i][j] = (f4v){0.f, 0.f, 0.f, 0.f};

#pragma unroll
  for (int c = 0; c < 2; c++) {
    int row = wave * 32 + c * 16 + grow;
    __builtin_amdgcn_global_load_lds(
        (gu32*)(xb + (size_t)(m0 + row) * NF + gsl * 8),
        (lu32*)&Al[0][wave * 32 + c * 16][0], 16, 0, 0);
    __builtin_amdgcn_global_load_lds(
        (gu32*)(WT + (size_t)(n0 + row) * NF + gsl * 8),
        (lu32*)&Bl[0][wave * 32 + c * 16][0], 16, 0, 0);
  }

#pragma unroll
  for (int ki = 0; ki < 16; ki++) {
    const int cur = ki & 1;
    __syncthreads();

    if (ki + 1 < 16) {
      const int kn = (ki + 1) * 32;
#pragma unroll
      for (int c = 0; c < 2; c++) {
        int row = wave * 32 + c * 16 + grow;
        __builtin_amdgcn_global_load_lds(
            (gu32*)(xb + (size_t)(m0 + row) * NF + kn + gsl * 8),
            (lu32*)&Al[cur ^ 1][wave * 32 + c * 16][0], 16, 0, 0);
        __builtin_amdgcn_global_load_lds(
            (gu32*)(WT + (size_t)(n0 + row) * NF + kn + gsl * 8),
            (lu32*)&Bl[cur ^ 1][wave * 32 + c * 16][0], 16, 0, 0);
      }
    }

    s8v af[4], bf[4];
#pragma unroll
    for (int f = 0; f < 4; f++) af[f] = *(const s8v*)&Al[cur][wm * 64 + f * 16 + lr][lg * 8];
#pragma unroll
    for (int f = 0; f < 4; f++) bf[f] = *(const s8v*)&Bl[cur][wn * 64 + f * 16 + lr][lg * 8];
#pragma unroll
    for (int i = 0; i < 4; i++)
#pragma unroll
      for (int j = 0; j < 4; j++)
        acc[i][j] = __builtin_amdgcn_mfma_f32_16x16x32_bf16(af[i], bf[j], acc[i][j], 0, 0, 0);
  }

#pragma unroll
  for (int i = 0; i < 4; i++) {
    int mbase = m0 + wm * 64 + i * 16 + lg * 4;
#pragma unroll
    for (int j = 0; j < 4; j++) {
      int n = n0 + wn * 64 + j * 16 + lr;
      float bval = bias[n];
      int h = n >> 6, d = n & 63;
      if (z == 2) {
        int b = mbase >> 12, s = mbase & 4095;
        s4v pk;
#pragma unroll
        for (int r = 0; r < 4; r++) pk[r] = f2bf(acc[i][j][r] + bval);
        *(s4v*)(vo + ((size_t)((b * 8 + h) * 64 + d)) * SLEN + s) = pk;
      } else {
        short* dst = (z == 0) ? qo : ko;
#pragma unroll
        for (int r = 0; r < 4; r++) {
          int m = mbase + r;
          int b = m >> 12, s = m & 4095;
          dst[((size_t)((b * 8 + h)) * SLEN + s) * 64 + d] = f2bf(acc[i][j][r] + bval);
        }
      }
    }
  }
}

// ---------------------------------------------------------------------------
// attn: r18-exact body (KVBLK=64, 32x32 MFMA, swapped QK^T, exp2 softmax
// fixed m=0, mask as MFMA C-init from global, ones-MFMA row-sum, reg-staged
// dbuf, XCD-clustered decode, SPLIT=1 direct bf16 ctx write).
// ---------------------------------------------------------------------------
template<int SPLIT>
__global__ __launch_bounds__(256) void attn(
    const short* __restrict__ q, const short* __restrict__ k,
    const short* __restrict__ vt, const float* __restrict__ maskl,
    short* __restrict__ ctx, float* __restrict__ poa, float* __restrict__ plc)
{
  const int KVLEN = SLEN / SPLIT;
  const int NT = KVLEN / 64;
  __shared__ short Kl[2][64][64];   // [buf][t][d], 16B slots XOR-swizzled by t&7
  __shared__ short Vl[2][64][64];   // [buf][d][t], swizzled by d&7

  const int tid = threadIdx.x;
  const int wave = tid >> 6, lane = tid & 63;
  const int h = lane >> 5, ln = lane & 31;

  const int x = blockIdx.x;
  const int c8 = x & 7, idx = x >> 3;
  const int bhsp = c8 + 8 * (idx >> 5);
  const int qb = idx & 31;
  const int bh = bhsp & 15;
  const int sp = bhsp >> 4;               // 0 for SPLIT=1
  const int bb = bh >> 3, hh = bh & 7;
  const int q0 = qb * 128 + wave * 32;

  const short* qp = q + ((size_t)bh * SLEN + q0 + ln) * 64 + h * 8;
  s8v qf[4];
#pragma unroll
  for (int d = 0; d < 4; d++) qf[d] = *(const s8v*)(qp + d * 16);

  s8v ones;
#pragma unroll
  for (int j = 0; j < 8; j++) ones[j] = (short)0x3F80;   // bf16 1.0

  f16v oa[2], lacc;
#pragma unroll
  for (int i = 0; i < 16; i++) { oa[0][i] = 0.f; oa[1][i] = 0.f; lacc[i] = 0.f; }

  const short* kg = k + (size_t)bh * SLEN * 64 + (size_t)sp * KVLEN * 64;
  const short* vg = vt + (size_t)bh * 64 * SLEN + (size_t)sp * KVLEN;
  const float* mp = maskl + (size_t)bb * SLEN + (size_t)sp * KVLEN;

  const int srow = tid >> 3, ss = tid & 7;
  const int sws = (ss ^ (srow & 7)) * 8;

  s8v kr0 = *(const s8v*)(kg + (size_t)srow * 64 + ss * 8);
  s8v kr1 = *(const s8v*)(kg + (size_t)(srow + 32) * 64 + ss * 8);
  s8v vr0 = *(const s8v*)(vg + (size_t)srow * SLEN + ss * 8);
  s8v vr1 = *(const s8v*)(vg + (size_t)(srow + 32) * SLEN + ss * 8);
  *(s8v*)&Kl[0][srow][sws] = kr0;  *(s8v*)&Kl[0][srow + 32][sws] = kr1;
  *(s8v*)&Vl[0][srow][sws] = vr0;  *(s8v*)&Vl[0][srow + 32][sws] = vr1;

  for (int it = 0; it < NT; ++it) {
    const int cur = it & 1;
    const int t0 = it * 64;
    __syncthreads();

    if (it + 1 < NT) {
      kr0 = *(const s8v*)(kg + (size_t)(t0 + 64 + srow) * 64 + ss * 8);
      kr1 = *(const s8v*)(kg + (size_t)(t0 + 96 + srow) * 64 + ss * 8);
      vr0 = *(const s8v*)(vg + (size_t)srow * SLEN + t0 + 64 + ss * 8);
      vr1 = *(const s8v*)(vg + (size_t)(srow + 32) * SLEN + t0 + 64 + ss * 8);
    }

    // ---- QK^T with mask (log2-domain) preloaded as accumulator C-init
    f16v sa[2];
#pragma unroll
    for (int tt = 0; tt < 2; tt++) {
#pragma unroll
      for (int q4 = 0; q4 < 4; q4++) {
        float4 mv = *(const float4*)(mp + t0 + tt * 32 + q4 * 8 + h * 4);
        sa[tt][q4 * 4 + 0] = mv.x;
        sa[tt][q4 * 4 + 1] = mv.y;
        sa[tt][q4 * 4 + 2] = mv.z;
        sa[tt][q4 * 4 + 3] = mv.w;
      }
    }
    __builtin_amdgcn_s_setprio(1);
#pragma unroll
    for (int tt = 0; tt < 2; tt++) {
#pragma unroll
      for (int ds_ = 0; ds_ < 4; ds_++) {
        s8v kf = *(const s8v*)&Kl[cur][tt * 32 + ln][(((ds_ * 2 + h) ^ (ln & 7))) * 8];
        sa[tt] = __builtin_amdgcn_mfma_f32_32x32x16_bf16(kf, qf[ds_], sa[tt], 0, 0, 0);
      }
    }
    __builtin_amdgcn_s_setprio(0);

    // ---- P = exp2(S), pack bf16 pairs
    unsigned int pku[2][4][2];
#pragma unroll
    for (int tt = 0; tt < 2; tt++)
#pragma unroll
      for (int q4 = 0; q4 < 4; q4++) {
        float p0, p1, p2, p3;
        asm("v_exp_f32 %0, %1" : "=v"(p0) : "v"(sa[tt][q4 * 4 + 0]));
        asm("v_exp_f32 %0, %1" : "=v"(p1) : "v"(sa[tt][q4 * 4 + 1]));
        asm("v_exp_f32 %0, %1" : "=v"(p2) : "v"(sa[tt][q4 * 4 + 2]));
        asm("v_exp_f32 %0, %1" : "=v"(p3) : "v"(sa[tt][q4 * 4 + 3]));
        unsigned int u0, u1;
        asm("v_cvt_pk_bf16_f32 %0, %1, %2" : "=v"(u0) : "v"(p0), "v"(p1));
        asm("v_cvt_pk_bf16_f32 %0, %1, %2" : "=v"(u1) : "v"(p2), "v"(p3));
        pku[tt][q4][0] = u0;
        pku[tt][q4][1] = u1;
      }

    // ---- PV + row-sum (ones-MFMA); A-frag via 2 shfls per ks
    __builtin_amdgcn_s_setprio(1);
#pragma unroll
    for (int ks = 0; ks < 4; ks++) {
      const int tt = ks >> 1, k1 = ks & 1;
      unsigned int s0 = h ? pku[tt][2 * k1][0] : pku[tt][2 * k1 + 1][0];
      unsigned int s1 = h ? pku[tt][2 * k1][1] : pku[tt][2 * k1 + 1][1];
      unsigned int r0 = (unsigned int)__shfl_xor((int)s0, 32);
      unsigned int r1 = (unsigned int)__shfl_xor((int)s1, 32);
      union { unsigned int u[4]; s8v v; } af;
      af.u[0] = h ? r0 : pku[tt][2 * k1][0];
      af.u[1] = h ? r1 : pku[tt][2 * k1][1];
      af.u[2] = h ? pku[tt][2 * k1 + 1][0] : r0;
      af.u[3] = h ? pku[tt][2 * k1 + 1][1] : r1;
      lacc = __builtin_amdgcn_mfma_f32_32x32x16_bf16(af.v, ones, lacc, 0, 0, 0);
#pragma unroll
      for (int dt = 0; dt < 2; dt++) {
        s8v vf = *(const s8v*)&Vl[cur][dt * 32 + ln][(((ks * 2 + h) ^ (ln & 7))) * 8];
        oa[dt] = __builtin_amdgcn_mfma_f32_32x32x16_bf16(af.v, vf, oa[dt], 0, 0, 0);
      }
    }
    __builtin_amdgcn_s_setprio(0);

    if (it + 1 < NT) {
      *(s8v*)&Kl[cur ^ 1][srow][sws] = kr0;  *(s8v*)&Kl[cur ^ 1][srow + 32][sws] = kr1;
      *(s8v*)&Vl[cur ^ 1][srow][sws] = vr0;  *(s8v*)&Vl[cur ^ 1][srow + 32][sws] = vr1;
    }
  }

  if constexpr (SPLIT == 1) {
#pragma unroll
    for (int q4 = 0; q4 < 4; q4++)
#pragma unroll
      for (int i = 0; i < 4; i++) {
        float inv = 1.0f / lacc[q4 * 4 + i];
        int qrow = q0 + i + q4 * 8 + 4 * h;
        size_t base = ((size_t)bb * SLEN + qrow) * NF + hh * 64;
        ctx[base + ln]      = f2bf(oa[0][q4 * 4 + i] * inv);
        ctx[base + 32 + ln] = f2bf(oa[1][q4 * 4 + i] * inv);
      }
  } else {
#pragma unroll
    for (int dt = 0; dt < 2; dt++) {
      size_t dbase = ((size_t)(sp * 16 + bh) * 64 + dt * 32 + ln) * SLEN;
#pragma unroll
      for (int q4 = 0; q4 < 4; q4++) {
        float4 v = {oa[dt][q4 * 4 + 0], oa[dt][q4 * 4 + 1],
                    oa[dt][q4 * 4 + 2], oa[dt][q4 * 4 + 3]};
        *(float4*)(poa + dbase + q0 + q4 * 8 + 4 * h) = v;
      }
    }
    if (ln == 0) {
      size_t lbase = (size_t)(sp * 16 + bh) * SLEN;
#pragma unroll
      for (int q4 = 0; q4 < 4; q4++) {
        float4 v = {lacc[q4 * 4 + 0], lacc[q4 * 4 + 1],
                    lacc[q4 * 4 + 2], lacc[q4 * 4 + 3]};
        *(float4*)(plc + lbase + q0 + q4 * 8 + 4 * h) = v;
      }
    }
  }
}

// ---------------------------------------------------------------------------
// out_proj: out[M,512] = ctx(bf16) @ WT[3] + bo  (fp32 out), gl_lds staging.
// ---------------------------------------------------------------------------
__global__ __launch_bounds__(256) void out_proj(
    const short* __restrict__ ctx, const short* __restrict__ wt,
    const float* __restrict__ bo, float* __restrict__ out)
{
  const short* WT = wt + (size_t)3 * NF * NF;
  const int m0 = blockIdx.x * 128;
  const int n0 = blockIdx.y * 128;
  __shared__ short Al[2][128][32];
  __shared__ short Bl[2][128][32];
  const int tid = threadIdx.x;
  const int wave = tid >> 6, lane = tid & 63;
  const int lg = lane >> 4, lr = lane & 15;
  const int wm = wave >> 1, wn = wave & 1;
  const int grow = lane >> 2;
  const int gsl  = lane & 3;

  f4v acc[4][4];
#pragma unroll
  for (int i = 0; i < 4; i++)
#pragma unroll
    for (int j = 0; j < 4; j++) acc[i][j] = (f4v){0.f, 0.f, 0.f, 0.f};

#pragma unroll
  for (int c = 0; c < 2; c++) {
    int row = wave * 32 + c * 16 + grow;
    __builtin_amdgcn_global_load_lds(
        (gu32*)(ctx + (size_t)(m0 + row) * NF + gsl * 8),
        (lu32*)&Al[0][wave * 32 + c * 16][0], 16, 0, 0);
    __builtin_amdgcn_global_load_lds(
        (gu32*)(WT + (size_t)(n0 + row) * NF + gsl * 8),
        (lu32*)&Bl[0][wave * 32 + c * 16][0], 16, 0, 0);
  }

#pragma unroll
  for (int ki = 0; ki < 16; ki++) {
    const int cur = ki & 1;
    __syncthreads();

    if (ki + 1 < 16) {
      const int kn = (ki + 1) * 32;
#pragma unroll
      for (int c = 0; c < 2; c++) {
        int row = wave * 32 + c * 16 + grow;
        __builtin_amdgcn_global_load_lds(
            (gu32*)(ctx + (size_t)(m0 + row) * NF + kn + gsl * 8),
            (lu32*)&Al[cur ^ 1][wave * 32 + c * 16][0], 16, 0, 0);
        __builtin_amdgcn_global_load_lds(
            (gu32*)(WT + (size_t)(n0 + row) * NF + kn + gsl * 8),
            (lu32*)&Bl[cur ^ 1][wave * 32 + c * 16][0], 16, 0, 0);
      }
    }

    s8v af[4], bf[4];
#pragma unroll
    for (int f = 0; f < 4; f++) af[f] = *(const s8v*)&Al[cur][wm * 64 + f * 16 + lr][lg * 8];
#pragma unroll
    for (int f = 0; f < 4; f++) bf[f] = *(const s8v*)&Bl[cur][wn * 64 + f * 16 + lr][lg * 8];
#pragma unroll
    for (int i = 0; i < 4; i++)
#pragma unroll
      for (int j = 0; j < 4; j++)
        acc[i][j] = __builtin_amdgcn_mfma_f32_16x16x32_bf16(af[i], bf[j], acc[i][j], 0, 0, 0);
  }

#pragma unroll
  for (int i = 0; i < 4; i++) {
    int mbase = m0 + wm * 64 + i * 16 + lg * 4;
#pragma unroll
    for (int j = 0; j < 4; j++) {
      int n = n0 + wn * 64 + j * 16 + lr;
      float bval = bo[n];
#pragma unroll
      for (int r = 0; r < 4; r++)
        out[(size_t)(mbase + r) * NF + n] = acc[i][j][r] + bval;
    }
  }
}

// ---------------------------------------------------------------------------
extern "C" void kernel_launch(void* const* d_in, const int* in_sizes, int n_in,
                              void* d_out, int out_size, void* d_ws, size_t ws_size,
                              hipStream_t stream) {
  const float* x    = (const float*)d_in[0];
  const float* mask = (const float*)d_in[1];
  const float* wq   = (const float*)d_in[2];
  const float* bq   = (const float*)d_in[3];
  const float* wk   = (const float*)d_in[4];
  const float* bk   = (const float*)d_in[5];
  const float* wv   = (const float*)d_in[6];
  const float* bv   = (const float*)d_in[7];
  const float* wo   = (const float*)d_in[8];
  const float* bo   = (const float*)d_in[9];
  float* out = (float*)d_out;

  char* ws = (char*)d_ws;
  const size_t MB = 1024ull * 1024ull;
  short* xb    = (short*)(ws);                 // 8 MB
  short* q_ws  = (short*)(ws + 8 * MB);        // 8 MB
  short* k_ws  = (short*)(ws + 16 * MB);       // 8 MB
  short* v_ws  = (short*)(ws + 24 * MB);       // 8 MB
  short* c_ws  = (short*)(ws + 32 * MB);       // 8 MB
  short* wt    = (short*)(ws + 40 * MB);       // 2 MB
  float* bqs   = (float*)(ws + 42 * MB);       // 2 KB
  float* maskl = (float*)(ws + 43 * MB);       // 32 KB
  float* poa   = (float*)(ws + 44 * MB);       // (SPLIT=2 fallback only)
  float* plc   = (float*)(ws + 76 * MB);

  prep_all<<<2313, 256, 0, stream>>>(x, bq, mask, wq, wk, wv, wo, xb, bqs, maskl, wt);
  qkv_proj<<<dim3(64, 4, 3), 256, 0, stream>>>(xb, wt, bqs, bk, bv, q_ws, k_ws, v_ws);
  attn<1><<<512, 256, 0, stream>>>(q_ws, k_ws, v_ws, maskl, c_ws, poa, plc);
  out_proj<<<dim3(64, 4), 256, 0, stream>>>(c_ws, wt, bo, out);
}